// Round 9
// baseline (84.177 us; speedup 1.0000x reference)
//
#include <hip/hip_runtime.h>

// PatchChamferDistance: B=32, G=64, P=256, D=3 -> BG=2048 patches.
// dist2[i][j] = ||p_i||^2 + ||t_j||^2 - 2 p_i.t_j (clamped >= 0)
// out = mean over patches of (mean_i min_j + mean_j min_i)
//
// Round 9 = round 7 (best: 81.1 us) + ONLY the jb x2 min3 pairing.
// r8's LDS-staged fragments regressed (per-ib ds_read_b128 serializes the
// loop head on lgkmcnt; r7's VALU-built frags overlap with MFMA issue) ->
// reverted. Established session facts:
//  - fusion regresses: r4 (fence storm on non-coherent per-XCD L2s),
//    r6 (single-line atomic bounce + smaller grid)
//  - harness floor ~75 us (41 us ws-poison fill @ 80% HBM peak + restores +
//    launches); kernel ~5 us, VALU-bound; MFMA pipe ~1 us, not binding
//  - C/D layout col=lane&15, row=quad*4+reg (m89-verified)
// Numerics: coords f16 RTNE (symmetric), tn split hi+lo (exact to ~1e-5),
// pn exact fp32 via C-init. absmax ~0 at threshold 7.93e-3.

#define NPATCH 2048
#define NPTS   256

typedef _Float16 f16x8 __attribute__((ext_vector_type(8)));
typedef float    f32x4 __attribute__((ext_vector_type(4)));

__global__ __launch_bounds__(256, 2) void chamfer_mfma_kernel(
    const float* __restrict__ pred,
    const float* __restrict__ tgt,
    float* __restrict__ partial)
{
    __shared__ __align__(16) float sP[4][4][NPTS];  // 4 patches x {x,y,z,norm}
    __shared__ __align__(16) float sT[4][4][NPTS];

    const int tid = threadIdx.x;

    // Stage 4 patches' SoA planes (whole block cooperates).
    {
        const size_t pbase = (size_t)blockIdx.x * 4 * (NPTS * 3);
#pragma unroll
        for (int pp = 0; pp < 4; ++pp) {
            const float* __restrict__ pb = pred + pbase + pp * (NPTS * 3);
            const float* __restrict__ tb = tgt  + pbase + pp * (NPTS * 3);
            float x = pb[3 * tid + 0], y = pb[3 * tid + 1], z = pb[3 * tid + 2];
            sP[pp][0][tid] = x; sP[pp][1][tid] = y; sP[pp][2][tid] = z;
            sP[pp][3][tid] = fmaf(z, z, fmaf(y, y, x * x));
            x = tb[3 * tid + 0]; y = tb[3 * tid + 1]; z = tb[3 * tid + 2];
            sT[pp][0][tid] = x; sT[pp][1][tid] = y; sT[pp][2][tid] = z;
            sT[pp][3][tid] = fmaf(z, z, fmaf(y, y, x * x));
        }
    }
    __syncthreads();

    const int wave = tid >> 6;      // one wave = one patch
    const int lane = tid & 63;
    const int c    = lane & 15;     // col within tile
    const int quad = lane >> 4;
    const bool q0  = (quad == 0);
    const int pp   = wave;

    const f16x8 zf = {};            // zero frag (quads 1-3 carry k>=8: all zero)

    // Build the 16 B-frags (target points) once; colmin accumulators.
    f16x8 bfrag[16];
    float colmin[16];
#pragma unroll
    for (int jb = 0; jb < 16; ++jb) {
        const int idx = jb * 16 + c;
        const float x = sT[pp][0][idx], y = sT[pp][1][idx], z = sT[pp][2][idx];
        const float tn = sT[pp][3][idx];
        const _Float16 th = (_Float16)tn;                 // RTNE
        const _Float16 tl = (_Float16)(tn - (float)th);   // residual
        f16x8 bv = {(_Float16)x, (_Float16)y, (_Float16)z, th, tl,
                    (_Float16)0, (_Float16)0, (_Float16)0};
        bfrag[jb] = q0 ? bv : zf;
        colmin[jb] = 1e30f;
    }

    float sf = 0.0f, sb = 0.0f;

#pragma unroll 1
    for (int ib = 0; ib < 16; ++ib) {
        // A-frag for this row-block: {-2x,-2y,-2z,1,1,0,0,0} on quad0.
        const int idx = ib * 16 + c;
        const float x = sP[pp][0][idx], y = sP[pp][1][idx], z = sP[pp][2][idx];
        f16x8 av = {(_Float16)(-2.0f * x), (_Float16)(-2.0f * y),
                    (_Float16)(-2.0f * z), (_Float16)1.0f, (_Float16)1.0f,
                    (_Float16)0, (_Float16)0, (_Float16)0};
        const f16x8 afrag = q0 ? av : zf;
        // C-init = pn for this lane's 4 rows (fp32 exact).
        const f32x4 pnv = *(const f32x4*)&sP[pp][3][ib * 16 + quad * 4];

        float r0 = 1e30f, r1 = 1e30f, r2 = 1e30f, r3 = 1e30f;
#pragma unroll
        for (int jb = 0; jb < 16; jb += 2) {
            const f32x4 d1 = __builtin_amdgcn_mfma_f32_16x16x32_f16(
                afrag, bfrag[jb], pnv, 0, 0, 0);
            const f32x4 d2 = __builtin_amdgcn_mfma_f32_16x16x32_f16(
                afrag, bfrag[jb + 1], pnv, 0, 0, 0);
            // rowmin: one v_min3 per accumulator over the MFMA pair
            r0 = fminf(r0, fminf(d1.x, d2.x));
            r1 = fminf(r1, fminf(d1.y, d2.y));
            r2 = fminf(r2, fminf(d1.z, d2.z));
            r3 = fminf(r3, fminf(d1.w, d2.w));
            // colmin: 2x v_min3 per tile
            const float t1 = fminf(fminf(d1.x, d1.y), d1.z);
            colmin[jb] = fminf(fminf(t1, d1.w), colmin[jb]);
            const float t2 = fminf(fminf(d2.x, d2.y), d2.z);
            colmin[jb + 1] = fminf(fminf(t2, d2.w), colmin[jb + 1]);
        }
        // rowmin: min over the 16 cols held by this quad's lanes.
#pragma unroll
        for (int dlt = 1; dlt < 16; dlt <<= 1) {
            r0 = fminf(r0, __shfl_xor(r0, dlt, 64));
            r1 = fminf(r1, __shfl_xor(r1, dlt, 64));
            r2 = fminf(r2, __shfl_xor(r2, dlt, 64));
            r3 = fminf(r3, __shfl_xor(r3, dlt, 64));
        }
        // each row now duplicated across 16 lanes -> scale by 1/16 later
        sf += fmaxf(r0, 0.0f) + fmaxf(r1, 0.0f) +
              fmaxf(r2, 0.0f) + fmaxf(r3, 0.0f);
    }

    // colmin: min across the 4 quads; each col duplicated x4 -> scale 1/4.
#pragma unroll
    for (int jb = 0; jb < 16; ++jb) {
        float v = colmin[jb];
        v = fminf(v, __shfl_xor(v, 16, 64));
        v = fminf(v, __shfl_xor(v, 32, 64));
        sb += fmaxf(v, 0.0f);
    }

    float tot = sf * (1.0f / 16.0f) + sb * (1.0f / 4.0f);
#pragma unroll
    for (int off = 32; off > 0; off >>= 1)
        tot += __shfl_down(tot, off, 64);
    if (lane == 0) partial[blockIdx.x * 4 + wave] = tot;
}

__global__ __launch_bounds__(256) void chamfer_reduce_kernel(
    const float* __restrict__ partial,
    float* __restrict__ out)
{
    __shared__ float red[4];
    const int tid = threadIdx.x;
    float s = 0.0f;
#pragma unroll
    for (int i = tid; i < NPATCH; i += 256) s += partial[i];
#pragma unroll
    for (int off = 32; off > 0; off >>= 1)
        s += __shfl_down(s, off, 64);
    if ((tid & 63) == 0) red[tid >> 6] = s;
    __syncthreads();
    if (tid == 0)
        out[0] = (red[0] + red[1] + red[2] + red[3]) *
                 (1.0f / ((float)NPTS * (float)NPATCH));
}

extern "C" void kernel_launch(void* const* d_in, const int* in_sizes, int n_in,
                              void* d_out, int out_size, void* d_ws, size_t ws_size,
                              hipStream_t stream) {
    const float* pred = (const float*)d_in[0];
    const float* tgt  = (const float*)d_in[1];
    float* partial    = (float*)d_ws;      // 2048 floats = 8 KB scratch
    float* out        = (float*)d_out;

    chamfer_mfma_kernel<<<NPATCH / 4, 256, 0, stream>>>(pred, tgt, partial);
    chamfer_reduce_kernel<<<1, 256, 0, stream>>>(partial, out);
}

// Round 10
// 81.344 us; speedup vs baseline: 1.0348x; 1.0348x over previous
//
#include <hip/hip_runtime.h>

// PatchChamferDistance: B=32, G=64, P=256, D=3 -> BG=2048 patches.
// dist2[i][j] = ||p_i||^2 + ||t_j||^2 - 2 p_i.t_j (clamped >= 0)
// out = mean over patches of (mean_i min_j + mean_j min_i)
//
// FINAL (round 10) = round 7 verbatim, the session's best measurement
// (81.1 us). Session findings:
//  - MFMA rewrite (r7): one mfma_f32_16x16x32_f16 = full 16x16 dist2 tile,
//    both chamfer directions reduced from the same tile. A = {-2x,-2y,-2z,
//    1,1,0..}, B = {x,y,z,tn_hi,tn_lo,0..} (tn split exact to ~1e-5),
//    C-init = fp32 pn. Cut kernel ~13 us (VALU) -> ~5 us.
//  - v_pk_fma_f32 is NOT dual-rate on CDNA4 (r3 neutral).
//  - Scalar-pipe streaming of the broadcast operand regresses (r2).
//  - Fusing the final reduction regresses: r4 (per-block fence+acq_rel =
//    L2 writeback storm on non-coherent per-XCD L2s), r6 (single-line
//    atomic bounce). Two-kernel skeleton is the proven shape.
//  - LDS-staged pre-converted fragments regress (r8: per-ib ds_read_b128
//    serializes the loop head; VALU-built frags overlap MFMA issue).
//  - Bench noise +-2-3 us > remaining headroom; total is ~92% harness-owned
//    (42 us ws-poison fill @ ~80% HBM peak + restores + launch gaps).
// C/D layout col=lane&15, row=quad*4+reg (m89-verified). absmax ~0 at
// threshold 7.93e-3 (f16 coord quantization, symmetric RTNE).

#define NPATCH 2048
#define NPTS   256

typedef _Float16 f16x8 __attribute__((ext_vector_type(8)));
typedef float    f32x4 __attribute__((ext_vector_type(4)));

__global__ __launch_bounds__(256, 2) void chamfer_mfma_kernel(
    const float* __restrict__ pred,
    const float* __restrict__ tgt,
    float* __restrict__ partial)
{
    __shared__ __align__(16) float sP[4][4][NPTS];  // 4 patches x {x,y,z,norm}
    __shared__ __align__(16) float sT[4][4][NPTS];

    const int tid = threadIdx.x;

    // Stage 4 patches' SoA planes (whole block cooperates).
    {
        const size_t pbase = (size_t)blockIdx.x * 4 * (NPTS * 3);
#pragma unroll
        for (int pp = 0; pp < 4; ++pp) {
            const float* __restrict__ pb = pred + pbase + pp * (NPTS * 3);
            const float* __restrict__ tb = tgt  + pbase + pp * (NPTS * 3);
            float x = pb[3 * tid + 0], y = pb[3 * tid + 1], z = pb[3 * tid + 2];
            sP[pp][0][tid] = x; sP[pp][1][tid] = y; sP[pp][2][tid] = z;
            sP[pp][3][tid] = fmaf(z, z, fmaf(y, y, x * x));
            x = tb[3 * tid + 0]; y = tb[3 * tid + 1]; z = tb[3 * tid + 2];
            sT[pp][0][tid] = x; sT[pp][1][tid] = y; sT[pp][2][tid] = z;
            sT[pp][3][tid] = fmaf(z, z, fmaf(y, y, x * x));
        }
    }
    __syncthreads();

    const int wave = tid >> 6;      // one wave = one patch
    const int lane = tid & 63;
    const int c    = lane & 15;     // col within tile
    const int quad = lane >> 4;
    const bool q0  = (quad == 0);
    const int pp   = wave;

    const f16x8 zf = {};            // zero frag (quads 1-3 carry k>=8: all zero)

    // Build the 16 B-frags (target points) once; colmin accumulators.
    f16x8 bfrag[16];
    float colmin[16];
#pragma unroll
    for (int jb = 0; jb < 16; ++jb) {
        const int idx = jb * 16 + c;
        const float x = sT[pp][0][idx], y = sT[pp][1][idx], z = sT[pp][2][idx];
        const float tn = sT[pp][3][idx];
        const _Float16 th = (_Float16)tn;                 // RTNE
        const _Float16 tl = (_Float16)(tn - (float)th);   // residual
        f16x8 bv = {(_Float16)x, (_Float16)y, (_Float16)z, th, tl,
                    (_Float16)0, (_Float16)0, (_Float16)0};
        bfrag[jb] = q0 ? bv : zf;
        colmin[jb] = 1e30f;
    }

    float sf = 0.0f, sb = 0.0f;

#pragma unroll 1
    for (int ib = 0; ib < 16; ++ib) {
        // A-frag for this row-block: {-2x,-2y,-2z,1,1,0,0,0} on quad0.
        const int idx = ib * 16 + c;
        const float x = sP[pp][0][idx], y = sP[pp][1][idx], z = sP[pp][2][idx];
        f16x8 av = {(_Float16)(-2.0f * x), (_Float16)(-2.0f * y),
                    (_Float16)(-2.0f * z), (_Float16)1.0f, (_Float16)1.0f,
                    (_Float16)0, (_Float16)0, (_Float16)0};
        const f16x8 afrag = q0 ? av : zf;
        // C-init = pn for this lane's 4 rows (fp32 exact).
        const f32x4 pnv = *(const f32x4*)&sP[pp][3][ib * 16 + quad * 4];

        float r0 = 1e30f, r1 = 1e30f, r2 = 1e30f, r3 = 1e30f;
#pragma unroll
        for (int jb = 0; jb < 16; ++jb) {
            const f32x4 d = __builtin_amdgcn_mfma_f32_16x16x32_f16(
                afrag, bfrag[jb], pnv, 0, 0, 0);
            r0 = fminf(r0, d.x); r1 = fminf(r1, d.y);
            r2 = fminf(r2, d.z); r3 = fminf(r3, d.w);
            const float t = fminf(fminf(d.x, d.y), d.z);          // v_min3
            colmin[jb] = fminf(fminf(t, d.w), colmin[jb]);        // v_min3
        }
        // rowmin: min over the 16 cols held by this quad's lanes.
#pragma unroll
        for (int dlt = 1; dlt < 16; dlt <<= 1) {
            r0 = fminf(r0, __shfl_xor(r0, dlt, 64));
            r1 = fminf(r1, __shfl_xor(r1, dlt, 64));
            r2 = fminf(r2, __shfl_xor(r2, dlt, 64));
            r3 = fminf(r3, __shfl_xor(r3, dlt, 64));
        }
        // each row now duplicated across 16 lanes -> scale by 1/16 later
        sf += fmaxf(r0, 0.0f) + fmaxf(r1, 0.0f) +
              fmaxf(r2, 0.0f) + fmaxf(r3, 0.0f);
    }

    // colmin: min across the 4 quads; each col duplicated x4 -> scale 1/4.
#pragma unroll
    for (int jb = 0; jb < 16; ++jb) {
        float v = colmin[jb];
        v = fminf(v, __shfl_xor(v, 16, 64));
        v = fminf(v, __shfl_xor(v, 32, 64));
        sb += fmaxf(v, 0.0f);
    }

    float tot = sf * (1.0f / 16.0f) + sb * (1.0f / 4.0f);
#pragma unroll
    for (int off = 32; off > 0; off >>= 1)
        tot += __shfl_down(tot, off, 64);
    if (lane == 0) partial[blockIdx.x * 4 + wave] = tot;
}

__global__ __launch_bounds__(256) void chamfer_reduce_kernel(
    const float* __restrict__ partial,
    float* __restrict__ out)
{
    __shared__ float red[4];
    const int tid = threadIdx.x;
    float s = 0.0f;
#pragma unroll
    for (int i = tid; i < NPATCH; i += 256) s += partial[i];
#pragma unroll
    for (int off = 32; off > 0; off >>= 1)
        s += __shfl_down(s, off, 64);
    if ((tid & 63) == 0) red[tid >> 6] = s;
    __syncthreads();
    if (tid == 0)
        out[0] = (red[0] + red[1] + red[2] + red[3]) *
                 (1.0f / ((float)NPTS * (float)NPATCH));
}

extern "C" void kernel_launch(void* const* d_in, const int* in_sizes, int n_in,
                              void* d_out, int out_size, void* d_ws, size_t ws_size,
                              hipStream_t stream) {
    const float* pred = (const float*)d_in[0];
    const float* tgt  = (const float*)d_in[1];
    float* partial    = (float*)d_ws;      // 2048 floats = 8 KB scratch
    float* out        = (float*)d_out;

    chamfer_mfma_kernel<<<NPATCH / 4, 256, 0, stream>>>(pred, tgt, partial);
    chamfer_reduce_kernel<<<1, 256, 0, stream>>>(partial, out);
}